// Round 9
// baseline (281.102 us; speedup 1.0000x reference)
//
#include <hip/hip_runtime.h>

typedef float f32x16 __attribute__((ext_vector_type(16)));
typedef int   i32x8  __attribute__((ext_vector_type(8)));

// ---------------- minifloat quantize (e4m3-style: E=4, M=3, bias=7) ----------------
// VALIDATED round 3: absmax 0.0 vs np reference. Used for bias + naive fallback.
__device__ __forceinline__ float quant1(float t) {
    unsigned bits = __float_as_uint(t);
    int eb = (int)((bits & 0x7fffffffu) >> 23);
    eb = eb < 121 ? 121 : eb;                     // clamp: e >= -6
    float m = __uint_as_float((unsigned)(257 - eb) << 23);  // 2^(3-e)
    float s = __uint_as_float((unsigned)(eb - 3) << 23);    // 2^(e-3)
    float q = rintf(t * m) * s;                   // RNE, matches np.round
    q = fminf(q, 240.0f);
    q = fmaxf(q, -240.0f);
    return q;
}

// Direct minifloat -> OCP e4m3fn encode. VALIDATED rounds 4-8 (absmax 0.0156 =
// pure accumulation-order noise, stable across replays).
__device__ __forceinline__ unsigned fp8enc(float t) {
    unsigned b  = __float_as_uint(t);
    unsigned sg = (b >> 24) & 0x80u;
    unsigned a  = b & 0x7fffffffu;
    unsigned mag;
    if (a < 0x3C800000u) {                          // |t| < 2^-6: subnormal grid
        mag = (unsigned)(int)rintf(__uint_as_float(a) * 512.0f);
    } else {
        mag = ((a + 0x7FFFFu + ((a >> 20) & 1u)) >> 20) - 0x3C0u;
        mag = mag > 0x77u ? 0x77u : mag;            // saturate at 240
    }
    return sg | mag;
}

// ------------- fused quantize + tile/swizzle kernel (x then w) ----------------------
// VALIDATED r5-r8. Per 128-row block, per K-tile (64 fp8), an 8192 B tile that IS
// the LDS image. Chunk c in [0,512): 16 B at row r=c>>2, physical slot p=c&3
// holding logical k-slot s = p ^ ((r>>1)&3).
__global__ void quant_tile_fp8_kernel(const float* __restrict__ x, const float* __restrict__ w,
                                      unsigned char* __restrict__ xq, unsigned char* __restrict__ wq,
                                      long long nAc, long long nTot, int K, int ktlog) {
    const long long stride = (long long)gridDim.x * blockDim.x;
    const int nktm1 = (1 << ktlog) - 1;
    for (long long chunk = (long long)blockIdx.x * blockDim.x + threadIdx.x;
         chunk < nTot; chunk += stride) {
        const bool isA = chunk < nAc;
        const float* src = isA ? x : w;
        unsigned char* dst = isA ? xq : wq;
        const long long cc = isA ? chunk : chunk - nAc;
        const long long tile = cc >> 9;
        const int c = (int)(cc & 511);
        const int r = c >> 2, p = c & 3;
        const int s = p ^ ((r >> 1) & 3);
        const long long blk = tile >> ktlog;
        const int kt0 = (int)(tile & nktm1);
        const float* s0 = src + (blk * 128 + r) * (long long)K + kt0 * 64 + s * 16;
        float4 a0 = *(const float4*)(s0);
        float4 a1 = *(const float4*)(s0 + 4);
        float4 b0 = *(const float4*)(s0 + 8);
        float4 b1 = *(const float4*)(s0 + 12);
        uint4 o;
        o.x = fp8enc(a0.x) | (fp8enc(a0.y) << 8) | (fp8enc(a0.z) << 16) | (fp8enc(a0.w) << 24);
        o.y = fp8enc(a1.x) | (fp8enc(a1.y) << 8) | (fp8enc(a1.z) << 16) | (fp8enc(a1.w) << 24);
        o.z = fp8enc(b0.x) | (fp8enc(b0.y) << 8) | (fp8enc(b0.z) << 16) | (fp8enc(b0.w) << 24);
        o.w = fp8enc(b1.x) | (fp8enc(b1.y) << 8) | (fp8enc(b1.z) << 16) | (fp8enc(b1.w) << 24);
        ((uint4*)dst)[cc] = o;   // linear: cc*16 == tile*8192 + c*16
    }
}

// --------- MX-scaled fp8 MFMA GEMM, counted-vmcnt double-buffer (T3-min/T4) ---------
#define BM 128
#define BN 128
#define BKB 64   /* fp8 per K-tile */

__device__ __forceinline__ void gload_lds16(const void* g, void* l) {
    __builtin_amdgcn_global_load_lds(
        (const __attribute__((address_space(1))) void*)g,
        (__attribute__((address_space(3))) void*)l, 16, 0, 0);
}

__global__ __launch_bounds__(256, 2) void gemm_fp8s_kernel(
    const unsigned char* __restrict__ At,  // [M/128][K/64][8192] pre-swizzled
    const unsigned char* __restrict__ Bt,  // [N/128][K/64][8192] pre-swizzled
    const float* __restrict__ bias,        // raw fp32, quantized in epilogue
    float* __restrict__ C, int M, int N, int K)
{
    __shared__ __align__(16) unsigned char As[2][BM * BKB];  // 2 x 8 KB
    __shared__ __align__(16) unsigned char Bs[2][BN * BKB];  // 2 x 8 KB

    const int t    = threadIdx.x;
    const int lane = t & 63;
    const int wid  = t >> 6;           // 4 waves: 2x2, each owns a 64x64 subtile
    const int wm   = (wid >> 1) * 64;
    const int wn   = (wid & 1) * 64;
    const int l31  = lane & 31;        // fragment row/col
    const int hi2  = lane >> 5;        // k-group 0..1 (32 fp8 each)

    const int nkt = K / BKB;
    const unsigned char* pA = At + (size_t)blockIdx.x * nkt * 8192;
    const unsigned char* pB = Bt + (size_t)blockIdx.y * nkt * 8192;

    // per-lane LDS byte offsets of logical slot s=2*hi2 for each 32x32 fragment;
    // the partner slot (s+1) lives at offset^16 (slots are XOR-permuted pairs)
    int offA[2], offB[2];
    #pragma unroll
    for (int mi = 0; mi < 2; ++mi) {
        int row = wm + mi * 32 + l31;
        offA[mi] = row * 64 + ((((hi2 << 1)) ^ ((row >> 1) & 3)) << 4);
    }
    #pragma unroll
    for (int ni = 0; ni < 2; ++ni) {
        int row = wn + ni * 32 + l31;
        offB[ni] = row * 64 + ((((hi2 << 1)) ^ ((row >> 1) & 3)) << 4);
    }

    f32x16 acc[2][2] = {};

    // prologue: stage tile 0 into buffer 0 (4 loads/wave in flight)
    gload_lds16(pA + t * 16,        &As[0][t * 16]);
    gload_lds16(pA + t * 16 + 4096, &As[0][t * 16 + 4096]);
    gload_lds16(pB + t * 16,        &Bs[0][t * 16]);
    gload_lds16(pB + t * 16 + 4096, &Bs[0][t * 16 + 4096]);

    for (int kt = 0; kt < nkt; ++kt) {
        const int cur = kt & 1;
        const bool more = (kt + 1) < nkt;

        if (more) {   // issue next-tile stage: these 4 loads stay in flight across
                      // both barriers and the whole MFMA phase (counted vmcnt below)
            const unsigned char* nA = pA + (size_t)(kt + 1) * 8192;
            const unsigned char* nB = pB + (size_t)(kt + 1) * 8192;
            gload_lds16(nA + t * 16,        &As[cur ^ 1][t * 16]);
            gload_lds16(nA + t * 16 + 4096, &As[cur ^ 1][t * 16 + 4096]);
            gload_lds16(nB + t * 16,        &Bs[cur ^ 1][t * 16]);
            gload_lds16(nB + t * 16 + 4096, &Bs[cur ^ 1][t * 16 + 4096]);
            // outstanding: 4 old (cur tile) + 4 new -> wait until only new remain
            asm volatile("s_waitcnt vmcnt(4)" ::: "memory");
        } else {
            asm volatile("s_waitcnt vmcnt(0)" ::: "memory");
        }
        __builtin_amdgcn_sched_barrier(0);
        __builtin_amdgcn_s_barrier();          // barrier 1: buf[cur] complete for all
        __builtin_amdgcn_sched_barrier(0);

        i32x8 av[2], bv[2];
        #pragma unroll
        for (int mi = 0; mi < 2; ++mi) {
            uint4 lo = *(const uint4*)&As[cur][offA[mi]];
            uint4 hi = *(const uint4*)&As[cur][offA[mi] ^ 16];
            i32x8 v; v[0]=(int)lo.x; v[1]=(int)lo.y; v[2]=(int)lo.z; v[3]=(int)lo.w;
                     v[4]=(int)hi.x; v[5]=(int)hi.y; v[6]=(int)hi.z; v[7]=(int)hi.w;
            av[mi] = v;
        }
        #pragma unroll
        for (int ni = 0; ni < 2; ++ni) {
            uint4 lo = *(const uint4*)&Bs[cur][offB[ni]];
            uint4 hi = *(const uint4*)&Bs[cur][offB[ni] ^ 16];
            i32x8 v; v[0]=(int)lo.x; v[1]=(int)lo.y; v[2]=(int)lo.z; v[3]=(int)lo.w;
                     v[4]=(int)hi.x; v[5]=(int)hi.y; v[6]=(int)hi.z; v[7]=(int)hi.w;
            bv[ni] = v;
        }

        #pragma unroll
        for (int mi = 0; mi < 2; ++mi)
            #pragma unroll
            for (int ni = 0; ni < 2; ++ni)
                // cbsz=0 (A fp8 e4m3), blgp=0 (B fp8 e4m3), scales 127 = E8M0 1.0
                acc[mi][ni] = __builtin_amdgcn_mfma_scale_f32_32x32x64_f8f6f4(
                    av[mi], bv[ni], acc[mi][ni], 0, 0, 0, 127, 0, 127);

        // ds_reads above are fully consumed (lgkmcnt waits precede MFMA issue), so
        // after this barrier iter kt+1 may safely overwrite buf[cur].
        __builtin_amdgcn_sched_barrier(0);
        asm volatile("s_waitcnt lgkmcnt(0)" ::: "memory");
        __builtin_amdgcn_s_barrier();          // barrier 2: all waves done reading cur
        __builtin_amdgcn_sched_barrier(0);
    }

    // ---- epilogue: 32x32 C/D layout col=lane&31, row=(reg&3)+8*(reg>>2)+4*(lane>>5)
    #pragma unroll
    for (int mi = 0; mi < 2; ++mi) {
        int row0 = blockIdx.x * BM + wm + mi * 32 + hi2 * 4;
        #pragma unroll
        for (int ni = 0; ni < 2; ++ni) {
            int col = blockIdx.y * BN + wn + ni * 32 + l31;
            float bb = quant1(bias[col]);
            #pragma unroll
            for (int reg = 0; reg < 16; ++reg) {
                int row = row0 + (reg & 3) + 8 * (reg >> 2);
                C[(size_t)row * N + col] = acc[mi][ni][reg] + bb;
            }
        }
    }
}

// ---------------- naive fallback (no workspace needed) ----------------
__global__ void naive_gemm_kernel(const float* __restrict__ x, const float* __restrict__ w,
                                  const float* __restrict__ b, float* __restrict__ out,
                                  int M, int N, int K) {
    int col = blockIdx.x * blockDim.x + threadIdx.x;
    int row = blockIdx.y;
    if (col >= N || row >= M) return;
    const float* xr = x + (size_t)row * K;
    const float* wr = w + (size_t)col * K;
    float acc = 0.f;
    for (int k = 0; k < K; ++k) acc += quant1(xr[k]) * quant1(wr[k]);
    out[(size_t)row * N + col] = acc + quant1(b[col]);
}

extern "C" void kernel_launch(void* const* d_in, const int* in_sizes, int n_in,
                              void* d_out, int out_size, void* d_ws, size_t ws_size,
                              hipStream_t stream) {
    const float* x = (const float*)d_in[0];
    const float* w = (const float*)d_in[1];
    const float* b = (const float*)d_in[2];
    float* out = (float*)d_out;

    const int xsz = in_sizes[0];
    const int wsz = in_sizes[1];
    const int N   = in_sizes[2];
    const int K   = wsz / N;
    const int M   = xsz / K;

    const size_t need = (size_t)xsz + (size_t)wsz;   // fp8: 1 B/elem
    const int nkt = K / BKB;
    const bool nkt_pow2 = nkt > 0 && (nkt & (nkt - 1)) == 0;

    const bool fast_ok = (ws_size >= need) && nkt_pow2 && (nkt >= 2) &&
                         (M % BM == 0) && (N % BN == 0) && (K % BKB == 0);

    if (fast_ok) {
        unsigned char* xq = (unsigned char*)d_ws;
        unsigned char* wq = (unsigned char*)d_ws + xsz;

        int ktlog = 0;
        while ((1 << ktlog) < nkt) ++ktlog;

        const long long nAc = (long long)xsz / 16;
        const long long nTot = nAc + (long long)wsz / 16;
        quant_tile_fp8_kernel<<<2048, 256, 0, stream>>>(x, w, xq, wq, nAc, nTot, K, ktlog);

        dim3 grid(M / BM, N / BN);
        gemm_fp8s_kernel<<<grid, 256, 0, stream>>>(xq, wq, b, out, M, N, K);
    } else {
        dim3 grid((N + 255) / 256, M);
        naive_gemm_kernel<<<grid, 256, 0, stream>>>(x, w, b, out, M, N, K);
    }
}